// Round 11
// baseline (581.343 us; speedup 1.0000x reference)
//
#include <hip/hip_runtime.h>
#include <cstdint>

typedef unsigned short u16;
typedef __attribute__((ext_vector_type(8))) short bf16x8;
typedef __attribute__((ext_vector_type(4))) float f32x4;

__device__ __forceinline__ u16 f2b(float x) {
  unsigned u = __float_as_uint(x);
  u += 0x7FFFu + ((u >> 16) & 1u);
  return (u16)(u >> 16);
}

__device__ __forceinline__ void gload16(const void* g, void* l) {
  __builtin_amdgcn_global_load_lds(
      (const __attribute__((address_space(1))) void*)g,
      (__attribute__((address_space(3))) void*)l, 16, 0, 0);
}

template <int N>
__device__ __forceinline__ void vmwait() {
  if constexpr (N == 0) asm volatile("s_waitcnt vmcnt(0)" ::: "memory");
  else if constexpr (N == 4) asm volatile("s_waitcnt vmcnt(4)" ::: "memory");
  else if constexpr (N == 6) asm volatile("s_waitcnt vmcnt(6)" ::: "memory");
}

// ---------------------------------------------------------------------------
// 128x32 bf16 slice as 64 virtual rows of 128 B (8 x 16 B chunks), chunk
// XOR (vrow&7): measured ZERO bank conflicts (r10). Both-sides rule (m231):
// LDS dest linear, global source inverse-swizzled, read same involution.
// ---------------------------------------------------------------------------
__device__ __forceinline__ void stage128(const u16* __restrict__ G,
                                         long long ld, int kb,
                                         u16* Ldst, int tid) {
#pragma unroll
  for (int j = 0; j < 2; ++j) {
    const int P = j * 256 + tid;
    const int vr = P >> 3;
    const int ch = (P & 7) ^ (vr & 7);
    const int r = vr * 2 + (ch >> 2), c = ch & 3;
    gload16(G + (long long)r * ld + kb + c * 8, Ldst + P * 8);
  }
}

__device__ __forceinline__ bf16x8 fr4(const u16* R, int row, int chunk) {
  const int vr = row >> 1;
  const int ch = (((row & 1) << 2) | chunk) ^ (vr & 7);
  return *(const bf16x8*)(R + vr * 64 + ch * 8);
}

// ---------------------------------------------------------------------------
// e3p: 128x128 tile, BK=32, 256 thr (4 waves 2x2, wave 64x64), 3x16KB LDS
// (3 blocks/CU), stage issued 2 iters ahead, counted vmcnt(4). (r10: 741 TF,
// MfmaUtil 31%, 0 conflicts.)
// EPI: 2=bf16  3=f32+colbias  4=f32 plain  6=bf16+rowbias
// ---------------------------------------------------------------------------
template <int EPI>
__global__ __launch_bounds__(256, 3) void e3p(
    const u16* __restrict__ A, long long lda, long long sAz,
    const u16* __restrict__ B, long long ldb, long long sBz,
    void* __restrict__ C0, long long ldc, long long sCz, int K,
    const float* __restrict__ b0) {
  constexpr int HALF = 4096;
  constexpr int BUFU = 2 * HALF;
  __shared__ __align__(16) u16 lds[3 * BUFU];

  const int gx = gridDim.x, S = gx * gridDim.y;
  const int hw = blockIdx.y * gx + blockIdx.x;
  const int l = (hw & 7) * (S >> 3) + (hw >> 3);
  const int bx = l % gx, by = l / gx;
  const int z = blockIdx.z;
  const long long tM = (long long)by * 128;
  const long long tN = (long long)bx * 128;
  const u16* GA = A + z * sAz + tM * lda;
  const u16* GB = B + z * sBz + tN * ldb;
  const int tid = threadIdx.x;
  const int NT = K >> 5;

  stage128(GA, lda, 0, lds, tid);
  stage128(GB, ldb, 0, lds + HALF, tid);
  stage128(GA, lda, 32, lds + BUFU, tid);
  stage128(GB, ldb, 32, lds + BUFU + HALF, tid);

  const int wid = tid >> 6, lane = tid & 63;
  const int wr = (wid >> 1) * 64, wc = (wid & 1) * 64;
  const int lr = lane & 15, cA = lane >> 4;
  f32x4 acc[4][4] = {};

  for (int t = 0; t < NT; ++t) {
    if (t < NT - 1) vmwait<4>(); else vmwait<0>();
    __builtin_amdgcn_s_barrier();
    if (t + 2 < NT) {
      u16* nxt = lds + ((t + 2) % 3) * BUFU;
      stage128(GA, lda, (t + 2) * 32, nxt, tid);
      stage128(GB, ldb, (t + 2) * 32, nxt + HALF, tid);
    }
    const u16* cur = lds + (t % 3) * BUFU;
    bf16x8 a[4], b[4];
#pragma unroll
    for (int m = 0; m < 4; ++m) a[m] = fr4(cur, wr + m * 16 + lr, cA);
#pragma unroll
    for (int n = 0; n < 4; ++n) b[n] = fr4(cur + HALF, wc + n * 16 + lr, cA);
#pragma unroll
    for (int m = 0; m < 4; ++m)
#pragma unroll
      for (int n = 0; n < 4; ++n)
        acc[m][n] = __builtin_amdgcn_mfma_f32_16x16x32_bf16(a[m], b[n],
                                                            acc[m][n], 0, 0, 0);
  }

  const int rr = (lane >> 4) << 2;
#pragma unroll
  for (int m = 0; m < 4; ++m) {
#pragma unroll
    for (int n = 0; n < 4; ++n) {
      const int col = (int)tN + wc + n * 16 + lr;
#pragma unroll
      for (int r = 0; r < 4; ++r) {
        const long long row = tM + wr + m * 16 + rr + r;
        const float v = acc[m][n][r];
        if constexpr (EPI == 2) {
          ((u16*)C0)[z * sCz + row * ldc + col] = f2b(v);
        } else if constexpr (EPI == 3) {
          ((float*)C0)[z * sCz + row * ldc + col] = v + b0[col];
        } else if constexpr (EPI == 4) {
          ((float*)C0)[z * sCz + row * ldc + col] = v;
        } else {  // 6: bf16 + row bias
          ((u16*)C0)[z * sCz + row * ldc + col] = f2b(v + b0[row]);
        }
      }
    }
  }
}

// ---------------------------------------------------------------------------
// e3w: 128x256 tile, BK=32, 256 thr (4 waves 2Mx2N, wave 64x128, 32 MFMA +
// 12 ds_read/iter), 3x24KB LDS (2 blocks/CU), same depth-2 counted pipeline.
// EPI 5 = mega-projection epilogue:
//   col group 0: Qcat[:, :1024]  = (v+bq)/32         (bf16)
//   col group 1: Kcat[:, :1024]  = v+bk              (bf16)
//   col group 2: Qcat[:,1024:]   = es*cos(pi*sig(v+bqt))
//   col group 3: Kcat[:,1024:]   = cos(pi*sig(v+bkt))
// ---------------------------------------------------------------------------
__device__ __forceinline__ void stage_w(const u16* GA, const u16* GB,
                                        long long lda, long long ldb,
                                        int kb, u16* buf, int tid) {
  stage128(GA, lda, kb, buf, tid);
  stage128(GB, ldb, kb, buf + 4096, tid);
  stage128(GB + 128 * ldb, ldb, kb, buf + 8192, tid);
}

__global__ __launch_bounds__(256, 2) void e3w(
    const u16* __restrict__ A, long long lda,
    const u16* __restrict__ B, long long ldb,
    u16* __restrict__ Qc, u16* __restrict__ Kc, int K,
    const float* __restrict__ b0, const float* __restrict__ b1,
    const float* __restrict__ b2, const float* __restrict__ b3,
    const float* __restrict__ esp) {
  constexpr int AS = 4096, BS = 8192;
  constexpr int BUFU = AS + BS;                 // 24 KB
  __shared__ __align__(16) u16 lds[3 * BUFU];   // 72 KB

  const int gx = gridDim.x, S = gx * gridDim.y;
  const int hw = blockIdx.y * gx + blockIdx.x;
  const int l = (hw & 7) * (S >> 3) + (hw >> 3);
  const int bx = l % gx, by = l / gx;
  const long long tM = (long long)by * 128;
  const long long tN = (long long)bx * 256;
  const u16* GA = A + tM * lda;
  const u16* GB = B + tN * ldb;
  const int tid = threadIdx.x;
  const int NT = K >> 5;

  stage_w(GA, GB, lda, ldb, 0, lds, tid);
  stage_w(GA, GB, lda, ldb, 32, lds + BUFU, tid);

  const int wid = tid >> 6, lane = tid & 63;
  const int wr = (wid >> 1) * 64, wc = (wid & 1) * 128;
  const int lr = lane & 15, cA = lane >> 4;
  f32x4 acc[4][8] = {};

  for (int t = 0; t < NT; ++t) {
    if (t < NT - 1) vmwait<6>(); else vmwait<0>();
    __builtin_amdgcn_s_barrier();
    if (t + 2 < NT)
      stage_w(GA, GB, lda, ldb, (t + 2) * 32, lds + ((t + 2) % 3) * BUFU, tid);
    const u16* cur = lds + (t % 3) * BUFU;
    const u16* Bs = cur + AS + (wid & 1) * 4096;   // wave's 128-row B sub
    bf16x8 a[4], b[8];
#pragma unroll
    for (int m = 0; m < 4; ++m) a[m] = fr4(cur, wr + m * 16 + lr, cA);
#pragma unroll
    for (int n = 0; n < 8; ++n) b[n] = fr4(Bs, n * 16 + lr, cA);
#pragma unroll
    for (int m = 0; m < 4; ++m)
#pragma unroll
      for (int n = 0; n < 8; ++n)
        acc[m][n] = __builtin_amdgcn_mfma_f32_16x16x32_bf16(a[m], b[n],
                                                            acc[m][n], 0, 0, 0);
  }

  const int rr = (lane >> 4) << 2;
  const float es = esp[0];
#pragma unroll
  for (int m = 0; m < 4; ++m) {
#pragma unroll
    for (int n = 0; n < 8; ++n) {
      const int col = (int)tN + wc + n * 16 + lr;
      const int g = col >> 10, cc = col & 1023;
#pragma unroll
      for (int r = 0; r < 4; ++r) {
        const long long row = tM + wr + m * 16 + rr + r;
        const float v = acc[m][n][r];
        if (g == 0) {
          Qc[row * 2048 + cc] = f2b((v + b0[cc]) * 0.03125f);
        } else if (g == 1) {
          Kc[row * 2048 + cc] = f2b(v + b1[cc]);
        } else if (g == 2) {
          const float tt = v + b2[cc];
          Qc[row * 2048 + 1024 + cc] = f2b(es * cospif(1.f / (1.f + __expf(-tt))));
        } else {
          const float tt = v + b3[cc];
          Kc[row * 2048 + 1024 + cc] = f2b(cospif(1.f / (1.f + __expf(-tt))));
        }
      }
    }
  }
}

// bqt[i] = sum_k bq[k]*Wt[k][i] + bt[i]; z=0 -> bq, z=1 -> bk
__global__ __launch_bounds__(256) void bias_fold(
    const float* __restrict__ bq, const float* __restrict__ bk,
    const float* __restrict__ Wt, const float* __restrict__ bt,
    float* __restrict__ out) {
  const int z = blockIdx.z;
  const float* bsrc = z ? bk : bq;
  float* dst = out + z * 1024;
  const int il = threadIdx.x & 127, ki = threadIdx.x >> 7;
  const int i = blockIdx.x * 128 + il;
  float acc = 0.f;
  for (int k = ki; k < 1024; k += 2)
    acc += bsrc[k] * Wt[(long long)k * 1024 + i];
  __shared__ float red[256];
  red[threadIdx.x] = acc;
  __syncthreads();
  if (ki == 0) dst[i] = red[il] + red[il + 128] + bt[i];
}

// row softmax over [8192][2048]: fp32 in-place + bf16 copy
__global__ __launch_bounds__(256) void softmax_rows(float* __restrict__ L,
                                                    u16* __restrict__ AB) {
  const long long row = blockIdx.x;
  float4* p4 = (float4*)(L + row * 2048);
  const int tid = threadIdx.x;
  float4 a = p4[tid], b = p4[tid + 256];
  float m = fmaxf(fmaxf(fmaxf(a.x, a.y), fmaxf(a.z, a.w)),
                  fmaxf(fmaxf(b.x, b.y), fmaxf(b.z, b.w)));
#pragma unroll
  for (int o = 32; o > 0; o >>= 1) m = fmaxf(m, __shfl_xor(m, o));
  __shared__ float rmax[4], rsum[4];
  const int wid = tid >> 6, lane = tid & 63;
  if (lane == 0) rmax[wid] = m;
  __syncthreads();
  m = fmaxf(fmaxf(rmax[0], rmax[1]), fmaxf(rmax[2], rmax[3]));
  a.x = __expf(a.x - m); a.y = __expf(a.y - m);
  a.z = __expf(a.z - m); a.w = __expf(a.w - m);
  b.x = __expf(b.x - m); b.y = __expf(b.y - m);
  b.z = __expf(b.z - m); b.w = __expf(b.w - m);
  float s = a.x + a.y + a.z + a.w + b.x + b.y + b.z + b.w;
#pragma unroll
  for (int o = 32; o > 0; o >>= 1) s += __shfl_xor(s, o);
  if (lane == 0) rsum[wid] = s;
  __syncthreads();
  s = rsum[0] + rsum[1] + rsum[2] + rsum[3];
  const float inv = 1.0f / s;
  a.x *= inv; a.y *= inv; a.z *= inv; a.w *= inv;
  b.x *= inv; b.y *= inv; b.z *= inv; b.w *= inv;
  p4[tid] = a;
  p4[tid + 256] = b;
  ushort4* o4 = (ushort4*)(AB + row * 2048);
  o4[tid]       = make_ushort4(f2b(a.x), f2b(a.y), f2b(a.z), f2b(a.w));
  o4[tid + 256] = make_ushort4(f2b(b.x), f2b(b.y), f2b(b.z), f2b(b.w));
}

__global__ __launch_bounds__(256) void cvt_x(const float* __restrict__ X,
                                             u16* __restrict__ XB) {
  const int i = blockIdx.x * 256 + threadIdx.x;
  float4 v = ((const float4*)X)[i];
  ((ushort4*)XB)[i] = make_ushort4(f2b(v.x), f2b(v.y), f2b(v.z), f2b(v.w));
}

// z 0..4: transpose+convert -> slots {0,1,4,5,6}; z 5..6: plain convert
// Wq,Wk -> slots {7,8}
__global__ void cvt_w(const float* __restrict__ W0, const float* __restrict__ W1,
                      const float* __restrict__ W2, const float* __restrict__ W3,
                      const float* __restrict__ W4, u16* __restrict__ WT) {
  __shared__ float t[32][33];
  const int z = blockIdx.z;
  const float* W = (z == 0 || z == 5) ? W0
                 : (z == 1 || z == 6) ? W1
                 : (z == 2) ? W2 : (z == 3) ? W3 : W4;
  const int slot = (z == 0) ? 0 : (z == 1) ? 1 : (z == 2) ? 4
                 : (z == 3) ? 5 : (z == 4) ? 6 : (z == 5) ? 7 : 8;
  u16* D = WT + ((long long)slot << 20);
  const int c0 = blockIdx.x * 32, r0 = blockIdx.y * 32;
  const int tx = threadIdx.x, ty = threadIdx.y;
  if (z >= 5) {
#pragma unroll
    for (int i = 0; i < 4; ++i) {
      const long long idx = (long long)(r0 + ty + i * 8) * 1024 + c0 + tx;
      D[idx] = f2b(W[idx]);
    }
    return;
  }
#pragma unroll
  for (int i = 0; i < 4; ++i)
    t[ty + i * 8][tx] = W[(long long)(r0 + ty + i * 8) * 1024 + c0 + tx];
  __syncthreads();
#pragma unroll
  for (int i = 0; i < 4; ++i)
    D[(long long)(c0 + ty + i * 8) * 1024 + r0 + tx] = f2b(t[tx][ty + i * 8]);
}

extern "C" void kernel_launch(void* const* d_in, const int* in_sizes, int n_in,
                              void* d_out, int out_size, void* d_ws,
                              size_t ws_size, hipStream_t stream) {
  const float* x  = (const float*)d_in[0];
  const float* Wq = (const float*)d_in[1];
  const float* bq = (const float*)d_in[2];
  const float* Wk = (const float*)d_in[3];
  const float* bk = (const float*)d_in[4];
  const float* Wv = (const float*)d_in[5];
  const float* bv = (const float*)d_in[6];
  const float* Wt = (const float*)d_in[7];
  const float* bt = (const float*)d_in[8];
  const float* Wo = (const float*)d_in[9];
  const float* bo = (const float*)d_in[10];
  const float* es = (const float*)d_in[11];

  char* ws = (char*)d_ws;
  // WT slots (1 MiB u16 each): 0=WqT 1=WkT 2=WqtT 3=WktT 4=WvT 5=WtT 6=WoT
  //                            7=WqB(plain) 8=WkB(plain)
  u16* WT     = (u16*)(ws);                    // 18.9 MB
  float* BQT  = (float*)(ws + 18874368);       // bqt[1024] | bkt[1024]
  u16* XB     = (u16*)(ws + 20971520);         // [8192,1024] bf16; later AV
  u16* Qcat   = (u16*)(ws + 37748736);         // [8192,2048]: Q/32 | es*r_q
  u16* Kcat   = (u16*)(ws + 71303168);         // [8192,2048]: K | r_k
  u16* VT     = (u16*)(ws + 104857600);        // [4][1024,2048] bf16
  u16* ATT    = Qcat;                          // attn bf16 reuse
  u16* AV     = XB;                            // attn@V bf16 reuse

  float* outO = (float*)d_out;                 // [4,2048,1024]
  float* outA = outO + 8388608;                // [4,2048,2048]

  cvt_x<<<8192, 256, 0, stream>>>(x, XB);
  cvt_w<<<dim3(32, 32, 7), dim3(32, 8), 0, stream>>>(Wq, Wk, Wv, Wt, Wo, WT);
  bias_fold<<<dim3(8, 1, 2), 256, 0, stream>>>(bq, bk, Wt, bt, BQT);
  // Wqt^T = WtT @ WqB^T, Wkt^T = WtT @ WkB^T  -> slots 2,3 (grid 128)
  e3p<2><<<dim3(8, 8, 2), 256, 0, stream>>>(
      WT + (5LL << 20), 1024, 0, WT + (7LL << 20), 1024, 1048576,
      WT + (2LL << 20), 1024, 1048576, 1024, nullptr);
  // mega-projection: X @ [Wq|Wk|Wqt|Wkt]^T -> Qcat,Kcat (grid 1024)
  e3w<<<dim3(16, 64, 1), 256, 0, stream>>>(
      XB, 1024, WT, 1024, Qcat, Kcat, 1024, bq, bk, BQT, BQT + 1024, es);
  // VT = Wv^T @ X^T (+bv by row) -> [4][1024,2048] (grid 512)
  e3p<6><<<dim3(16, 8, 4), 256, 0, stream>>>(
      WT + (4LL << 20), 1024, 0, XB, 1024, 2097152,
      VT, 2048, 2097152, 1024, bv);
  // logits = Qcat @ Kcat^T (K=2048) -> outA (grid 1024)
  e3p<4><<<dim3(16, 16, 4), 256, 0, stream>>>(
      Qcat, 2048, 4194304, Kcat, 2048, 4194304,
      outA, 2048, 4194304, 2048, nullptr);
  softmax_rows<<<8192, 256, 0, stream>>>(outA, ATT);
  // attn @ V (grid 512)
  e3p<2><<<dim3(8, 16, 4), 256, 0, stream>>>(
      ATT, 2048, 4194304, VT, 2048, 2097152,
      AV, 1024, 2097152, 2048, nullptr);
  // output projection (grid 512)
  e3p<3><<<dim3(8, 64, 1), 256, 0, stream>>>(
      AV, 1024, 0, WT + (6LL << 20), 1024, 0,
      outO, 1024, 0, 1024, bo);
}

// Round 12
// 484.699 us; speedup vs baseline: 1.1994x; 1.1994x over previous
//
#include <hip/hip_runtime.h>
#include <cstdint>

typedef unsigned short u16;
typedef __attribute__((ext_vector_type(8))) short bf16x8;
typedef __attribute__((ext_vector_type(4))) float f32x4;

__device__ __forceinline__ u16 f2b(float x) {
  unsigned u = __float_as_uint(x);
  u += 0x7FFFu + ((u >> 16) & 1u);
  return (u16)(u >> 16);
}

__device__ __forceinline__ void gload16(const void* g, void* l) {
  __builtin_amdgcn_global_load_lds(
      (const __attribute__((address_space(1))) void*)g,
      (__attribute__((address_space(3))) void*)l, 16, 0, 0);
}

template <int N>
__device__ __forceinline__ void vmwait() {
  if constexpr (N == 0) asm volatile("s_waitcnt vmcnt(0)" ::: "memory");
  else if constexpr (N == 4) asm volatile("s_waitcnt vmcnt(4)" ::: "memory");
}

// ---------------------------------------------------------------------------
// 128x32 bf16 slice as 64 virtual rows of 128 B (8 x 16 B chunks), chunk
// XOR (vrow&7): measured ZERO bank conflicts (r10). Both-sides rule (m231):
// LDS dest linear, global source inverse-swizzled, read same involution.
// ---------------------------------------------------------------------------
__device__ __forceinline__ void stage128(const u16* __restrict__ G,
                                         long long ld, int kb,
                                         u16* Ldst, int tid) {
#pragma unroll
  for (int j = 0; j < 2; ++j) {
    const int P = j * 256 + tid;
    const int vr = P >> 3;
    const int ch = (P & 7) ^ (vr & 7);
    const int r = vr * 2 + (ch >> 2), c = ch & 3;
    gload16(G + (long long)r * ld + kb + c * 8, Ldst + P * 8);
  }
}

__device__ __forceinline__ bf16x8 fr4(const u16* R, int row, int chunk) {
  const int vr = row >> 1;
  const int ch = (((row & 1) << 2) | chunk) ^ (vr & 7);
  return *(const bf16x8*)(R + vr * 64 + ch * 8);
}

// ---------------------------------------------------------------------------
// e3p: 128x128 tile, BK=32, 256 thr (4 waves 2x2, wave 64x64), 3x16KB LDS
// (3 blocks/CU), stage issued 2 iters ahead, counted vmcnt(4). (r10: 741 TF,
// MfmaUtil 31%, 0 bank conflicts.)
// EPI: 2=bf16  3=f32+colbias  4=f32 plain
// ---------------------------------------------------------------------------
template <int EPI>
__global__ __launch_bounds__(256, 3) void e3p(
    const u16* __restrict__ A, long long lda, long long sAz,
    const u16* __restrict__ B, long long ldb, long long sBz,
    void* __restrict__ C0, long long ldc, long long sCz, int K,
    const float* __restrict__ b0) {
  constexpr int HALF = 4096;
  constexpr int BUFU = 2 * HALF;
  __shared__ __align__(16) u16 lds[3 * BUFU];

  const int gx = gridDim.x, S = gx * gridDim.y;
  const int hw = blockIdx.y * gx + blockIdx.x;
  const int l = (hw & 7) * (S >> 3) + (hw >> 3);
  const int bx = l % gx, by = l / gx;
  const int z = blockIdx.z;
  const long long tM = (long long)by * 128;
  const long long tN = (long long)bx * 128;
  const u16* GA = A + z * sAz + tM * lda;
  const u16* GB = B + z * sBz + tN * ldb;
  const int tid = threadIdx.x;
  const int NT = K >> 5;

  stage128(GA, lda, 0, lds, tid);
  stage128(GB, ldb, 0, lds + HALF, tid);
  stage128(GA, lda, 32, lds + BUFU, tid);
  stage128(GB, ldb, 32, lds + BUFU + HALF, tid);

  const int wid = tid >> 6, lane = tid & 63;
  const int wr = (wid >> 1) * 64, wc = (wid & 1) * 64;
  const int lr = lane & 15, cA = lane >> 4;
  f32x4 acc[4][4] = {};

  for (int t = 0; t < NT; ++t) {
    if (t < NT - 1) vmwait<4>(); else vmwait<0>();
    __builtin_amdgcn_s_barrier();
    if (t + 2 < NT) {
      u16* nxt = lds + ((t + 2) % 3) * BUFU;
      stage128(GA, lda, (t + 2) * 32, nxt, tid);
      stage128(GB, ldb, (t + 2) * 32, nxt + HALF, tid);
    }
    const u16* cur = lds + (t % 3) * BUFU;
    bf16x8 a[4], b[4];
#pragma unroll
    for (int m = 0; m < 4; ++m) a[m] = fr4(cur, wr + m * 16 + lr, cA);
#pragma unroll
    for (int n = 0; n < 4; ++n) b[n] = fr4(cur + HALF, wc + n * 16 + lr, cA);
#pragma unroll
    for (int m = 0; m < 4; ++m)
#pragma unroll
      for (int n = 0; n < 4; ++n)
        acc[m][n] = __builtin_amdgcn_mfma_f32_16x16x32_bf16(a[m], b[n],
                                                            acc[m][n], 0, 0, 0);
  }

  const int rr = (lane >> 4) << 2;
#pragma unroll
  for (int m = 0; m < 4; ++m) {
#pragma unroll
    for (int n = 0; n < 4; ++n) {
      const int col = (int)tN + wc + n * 16 + lr;
#pragma unroll
      for (int r = 0; r < 4; ++r) {
        const long long row = tM + wr + m * 16 + rr + r;
        const float v = acc[m][n][r];
        if constexpr (EPI == 2) {
          ((u16*)C0)[z * sCz + row * ldc + col] = f2b(v);
        } else if constexpr (EPI == 3) {
          ((float*)C0)[z * sCz + row * ldc + col] = v + b0[col];
        } else {
          ((float*)C0)[z * sCz + row * ldc + col] = v;
        }
      }
    }
  }
}

// ---------------------------------------------------------------------------
// mega: e3p clone, z-split projection X @ W(z)^T, W(z) = WT + z<<20
// (slots 0..3 = WqT,WkT,WqtT,WktT). Per-z epilogue:
//  z0: Qc[:, :1024] = (v+bq)/32          z1: Kc[:, :1024] = v+bk
//  z2: Qc[:,1024:]  = es*cospi(sig(v+bqt)) z3: Kc[:,1024:] = cospi(sig(v+bkt))
// ---------------------------------------------------------------------------
__global__ __launch_bounds__(256, 3) void mega(
    const u16* __restrict__ XB_, const u16* __restrict__ Wbase,
    u16* __restrict__ Qc, u16* __restrict__ Kc,
    const float* __restrict__ bq, const float* __restrict__ bk,
    const float* __restrict__ BF, const float* __restrict__ esp) {
  constexpr int HALF = 4096;
  constexpr int BUFU = 2 * HALF;
  __shared__ __align__(16) u16 lds[3 * BUFU];

  const int gx = gridDim.x, S = gx * gridDim.y;
  const int hw = blockIdx.y * gx + blockIdx.x;
  const int l = (hw & 7) * (S >> 3) + (hw >> 3);
  const int bx = l % gx, by = l / gx;
  const int z = blockIdx.z;
  const long long tM = (long long)by * 128;
  const long long tN = (long long)bx * 128;
  const u16* GA = XB_ + tM * 1024;
  const u16* GB = Wbase + ((long long)z << 20) + tN * 1024;
  const int tid = threadIdx.x;
  const int NT = 32;  // K=1024

  stage128(GA, 1024, 0, lds, tid);
  stage128(GB, 1024, 0, lds + HALF, tid);
  stage128(GA, 1024, 32, lds + BUFU, tid);
  stage128(GB, 1024, 32, lds + BUFU + HALF, tid);

  const int wid = tid >> 6, lane = tid & 63;
  const int wr = (wid >> 1) * 64, wc = (wid & 1) * 64;
  const int lr = lane & 15, cA = lane >> 4;
  f32x4 acc[4][4] = {};

  for (int t = 0; t < NT; ++t) {
    if (t < NT - 1) vmwait<4>(); else vmwait<0>();
    __builtin_amdgcn_s_barrier();
    if (t + 2 < NT) {
      u16* nxt = lds + ((t + 2) % 3) * BUFU;
      stage128(GA, 1024, (t + 2) * 32, nxt, tid);
      stage128(GB, 1024, (t + 2) * 32, nxt + HALF, tid);
    }
    const u16* cur = lds + (t % 3) * BUFU;
    bf16x8 a[4], b[4];
#pragma unroll
    for (int m = 0; m < 4; ++m) a[m] = fr4(cur, wr + m * 16 + lr, cA);
#pragma unroll
    for (int n = 0; n < 4; ++n) b[n] = fr4(cur + HALF, wc + n * 16 + lr, cA);
#pragma unroll
    for (int m = 0; m < 4; ++m)
#pragma unroll
      for (int n = 0; n < 4; ++n)
        acc[m][n] = __builtin_amdgcn_mfma_f32_16x16x32_bf16(a[m], b[n],
                                                            acc[m][n], 0, 0, 0);
  }

  const int rr = (lane >> 4) << 2;
  const float es = esp[0];
#pragma unroll
  for (int m = 0; m < 4; ++m) {
#pragma unroll
    for (int n = 0; n < 4; ++n) {
      const int col = (int)tN + wc + n * 16 + lr;  // 0..1023
#pragma unroll
      for (int r = 0; r < 4; ++r) {
        const long long row = tM + wr + m * 16 + rr + r;
        const float v = acc[m][n][r];
        if (z == 0) {
          Qc[row * 2048 + col] = f2b((v + bq[col]) * 0.03125f);
        } else if (z == 1) {
          Kc[row * 2048 + col] = f2b(v + bk[col]);
        } else if (z == 2) {
          const float tt = v + BF[col];
          Qc[row * 2048 + 1024 + col] =
              f2b(es * cospif(1.f / (1.f + __expf(-tt))));
        } else {
          const float tt = v + BF[1024 + col];
          Kc[row * 2048 + 1024 + col] =
              f2b(cospif(1.f / (1.f + __expf(-tt))));
        }
      }
    }
  }
}

// folds: z0: bqt = bq@Wt + bt; z1: bkt = bk@Wt + bt; z2: bfin = bv@Wo + bo
__global__ __launch_bounds__(256) void bias_fold(
    const float* __restrict__ bq, const float* __restrict__ bk,
    const float* __restrict__ bv, const float* __restrict__ Wt,
    const float* __restrict__ Wo, const float* __restrict__ bt,
    const float* __restrict__ bo, float* __restrict__ out) {
  const int z = blockIdx.z;
  const float* bsrc = (z == 0) ? bq : (z == 1) ? bk : bv;
  const float* W = (z == 2) ? Wo : Wt;
  const float* badd = (z == 2) ? bo : bt;
  float* dst = out + z * 1024;
  const int il = threadIdx.x & 127, ki = threadIdx.x >> 7;
  const int i = blockIdx.x * 128 + il;
  float acc = 0.f;
  for (int k = ki; k < 1024; k += 2)
    acc += bsrc[k] * W[(long long)k * 1024 + i];
  __shared__ float red[256];
  red[threadIdx.x] = acc;
  __syncthreads();
  if (ki == 0) dst[i] = red[il] + red[il + 128] + badd[i];
}

// row softmax over [8192][2048]: fp32 in-place + bf16 copy
__global__ __launch_bounds__(256) void softmax_rows(float* __restrict__ L,
                                                    u16* __restrict__ AB) {
  const long long row = blockIdx.x;
  float4* p4 = (float4*)(L + row * 2048);
  const int tid = threadIdx.x;
  float4 a = p4[tid], b = p4[tid + 256];
  float m = fmaxf(fmaxf(fmaxf(a.x, a.y), fmaxf(a.z, a.w)),
                  fmaxf(fmaxf(b.x, b.y), fmaxf(b.z, b.w)));
#pragma unroll
  for (int o = 32; o > 0; o >>= 1) m = fmaxf(m, __shfl_xor(m, o));
  __shared__ float rmax[4], rsum[4];
  const int wid = tid >> 6, lane = tid & 63;
  if (lane == 0) rmax[wid] = m;
  __syncthreads();
  m = fmaxf(fmaxf(rmax[0], rmax[1]), fmaxf(rmax[2], rmax[3]));
  a.x = __expf(a.x - m); a.y = __expf(a.y - m);
  a.z = __expf(a.z - m); a.w = __expf(a.w - m);
  b.x = __expf(b.x - m); b.y = __expf(b.y - m);
  b.z = __expf(b.z - m); b.w = __expf(b.w - m);
  float s = a.x + a.y + a.z + a.w + b.x + b.y + b.z + b.w;
#pragma unroll
  for (int o = 32; o > 0; o >>= 1) s += __shfl_xor(s, o);
  if (lane == 0) rsum[wid] = s;
  __syncthreads();
  s = rsum[0] + rsum[1] + rsum[2] + rsum[3];
  const float inv = 1.0f / s;
  a.x *= inv; a.y *= inv; a.z *= inv; a.w *= inv;
  b.x *= inv; b.y *= inv; b.z *= inv; b.w *= inv;
  p4[tid] = a;
  p4[tid + 256] = b;
  ushort4* o4 = (ushort4*)(AB + row * 2048);
  o4[tid]       = make_ushort4(f2b(a.x), f2b(a.y), f2b(a.z), f2b(a.w));
  o4[tid + 256] = make_ushort4(f2b(b.x), f2b(b.y), f2b(b.z), f2b(b.w));
}

__global__ __launch_bounds__(256) void cvt_x(const float* __restrict__ X,
                                             u16* __restrict__ XB) {
  const int i = blockIdx.x * 256 + threadIdx.x;
  float4 v = ((const float4*)X)[i];
  ((ushort4*)XB)[i] = make_ushort4(f2b(v.x), f2b(v.y), f2b(v.z), f2b(v.w));
}

// z0..3: transpose {Wq->0, Wk->1, Wt->5, Wo->6}; z4..6: plain {Wq->7,Wk->8,Wv->9}
__global__ void cvt_w(const float* __restrict__ Wq, const float* __restrict__ Wk,
                      const float* __restrict__ Wv, const float* __restrict__ Wt,
                      const float* __restrict__ Wo, u16* __restrict__ WT) {
  __shared__ float t[32][33];
  const int z = blockIdx.z;
  const float* W = (z == 0 || z == 4) ? Wq
                 : (z == 1 || z == 5) ? Wk
                 : (z == 2) ? Wt : (z == 3) ? Wo : Wv;
  const int slot = (z == 0) ? 0 : (z == 1) ? 1 : (z == 2) ? 5
                 : (z == 3) ? 6 : (z == 4) ? 7 : (z == 5) ? 8 : 9;
  u16* D = WT + ((long long)slot << 20);
  const int c0 = blockIdx.x * 32, r0 = blockIdx.y * 32;
  const int tx = threadIdx.x, ty = threadIdx.y;
  if (z >= 4) {
#pragma unroll
    for (int i = 0; i < 4; ++i) {
      const long long idx = (long long)(r0 + ty + i * 8) * 1024 + c0 + tx;
      D[idx] = f2b(W[idx]);
    }
    return;
  }
#pragma unroll
  for (int i = 0; i < 4; ++i)
    t[ty + i * 8][tx] = W[(long long)(r0 + ty + i * 8) * 1024 + c0 + tx];
  __syncthreads();
#pragma unroll
  for (int i = 0; i < 4; ++i)
    D[(long long)(c0 + ty + i * 8) * 1024 + r0 + tx] = f2b(t[tx][ty + i * 8]);
}

extern "C" void kernel_launch(void* const* d_in, const int* in_sizes, int n_in,
                              void* d_out, int out_size, void* d_ws,
                              size_t ws_size, hipStream_t stream) {
  const float* x  = (const float*)d_in[0];
  const float* Wq = (const float*)d_in[1];
  const float* bq = (const float*)d_in[2];
  const float* Wk = (const float*)d_in[3];
  const float* bk = (const float*)d_in[4];
  const float* Wv = (const float*)d_in[5];
  const float* bv = (const float*)d_in[6];
  const float* Wt = (const float*)d_in[7];
  const float* bt = (const float*)d_in[8];
  const float* Wo = (const float*)d_in[9];
  const float* bo = (const float*)d_in[10];
  const float* es = (const float*)d_in[11];

  char* ws = (char*)d_ws;
  // WT slots (1 MiB-u16 each): 0=WqT 1=WkT 2=WqtT 3=WktT 4=WvoT 5=WtT 6=WoT
  //                            7=WqB 8=WkB 9=WvB
  u16* WT    = (u16*)(ws);                   // 20 MB
  float* BF  = (float*)(ws + 20971520);      // [3][1024]: bqt | bkt | bfin
  u16* XB    = (u16*)(ws + 20983808);        // [8192,1024] bf16
  u16* Qcat  = (u16*)(ws + 37761024);        // [8192,2048]: Q/32 | es*r_q
  u16* Kcat  = (u16*)(ws + 71315456);        // [8192,2048]: K | r_k
  u16* XVT   = (u16*)(ws + 104869888);       // [4][1024,2048]: (x@Wvo)^T
  u16* ATT   = Qcat;                         // attn bf16 reuse

  float* outO = (float*)d_out;               // [4,2048,1024]
  float* outA = outO + 8388608;              // [4,2048,2048]

  cvt_x<<<8192, 256, 0, stream>>>(x, XB);
  cvt_w<<<dim3(32, 32, 7), dim3(32, 8), 0, stream>>>(Wq, Wk, Wv, Wt, Wo, WT);
  bias_fold<<<dim3(8, 1, 3), 256, 0, stream>>>(bq, bk, bv, Wt, Wo, bt, bo, BF);
  // WqtT = WtT@WqB^T, WktT = WtT@WkB^T -> slots 2,3 (grid 128)
  e3p<2><<<dim3(8, 8, 2), 256, 0, stream>>>(
      WT + (5LL << 20), 1024, 0, WT + (7LL << 20), 1024, 1048576,
      WT + (2LL << 20), 1024, 1048576, 1024, nullptr);
  // WvoT = WoT@WvB^T -> slot 4 (grid 64)
  e3p<2><<<dim3(8, 8, 1), 256, 0, stream>>>(
      WT + (6LL << 20), 1024, 0, WT + (9LL << 20), 1024, 0,
      WT + (4LL << 20), 1024, 0, 1024, nullptr);
  // mega projection -> Qcat, Kcat (grid 2048)
  mega<<<dim3(8, 64, 4), 256, 0, stream>>>(XB, WT, Qcat, Kcat, bq, bk, BF, es);
  // XVT = WvoT @ XB^T  (grid 512)
  e3p<2><<<dim3(16, 8, 4), 256, 0, stream>>>(
      WT + (4LL << 20), 1024, 0, XB, 1024, 2097152,
      XVT, 2048, 2097152, 1024, nullptr);
  // logits = Qcat @ Kcat^T (K=2048) -> outA (grid 1024)
  e3p<4><<<dim3(16, 16, 4), 256, 0, stream>>>(
      Qcat, 2048, 4194304, Kcat, 2048, 4194304,
      outA, 2048, 4194304, 2048, nullptr);
  softmax_rows<<<8192, 256, 0, stream>>>(outA, ATT);
  // out = ATT @ XVT^T + bfin  (grid 512)
  e3p<3><<<dim3(8, 16, 4), 256, 0, stream>>>(
      ATT, 2048, 4194304, XVT, 2048, 2097152,
      outO, 1024, 2097152, 2048, BF + 2048);
}

// Round 13
// 339.484 us; speedup vs baseline: 1.7124x; 1.4278x over previous
//
#include <hip/hip_runtime.h>
#include <cstdint>

typedef unsigned short u16;
typedef __attribute__((ext_vector_type(8))) short bf16x8;
typedef __attribute__((ext_vector_type(4))) float f32x4;

__device__ __forceinline__ u16 f2b(float x) {
  unsigned u = __float_as_uint(x);
  u += 0x7FFFu + ((u >> 16) & 1u);
  return (u16)(u >> 16);
}

__device__ __forceinline__ void gload16(const void* g, void* l) {
  __builtin_amdgcn_global_load_lds(
      (const __attribute__((address_space(1))) void*)g,
      (__attribute__((address_space(3))) void*)l, 16, 0, 0);
}

template <int N>
__device__ __forceinline__ void vmwait() {
  if constexpr (N == 0) asm volatile("s_waitcnt vmcnt(0)" ::: "memory");
  else if constexpr (N == 4) asm volatile("s_waitcnt vmcnt(4)" ::: "memory");
}

// ---------------------------------------------------------------------------
// 128x32 bf16 slice as 64 virtual rows of 128 B (8 x 16 B chunks), chunk
// XOR (vrow&7): measured ZERO bank conflicts (r10). Both-sides rule (m231):
// LDS dest linear, global source inverse-swizzled, read same involution.
// ---------------------------------------------------------------------------
__device__ __forceinline__ void stage128(const u16* __restrict__ G,
                                         long long ld, int kb,
                                         u16* Ldst, int tid) {
#pragma unroll
  for (int j = 0; j < 2; ++j) {
    const int P = j * 256 + tid;
    const int vr = P >> 3;
    const int ch = (P & 7) ^ (vr & 7);
    const int r = vr * 2 + (ch >> 2), c = ch & 3;
    gload16(G + (long long)r * ld + kb + c * 8, Ldst + P * 8);
  }
}

__device__ __forceinline__ bf16x8 fr4(const u16* R, int row, int chunk) {
  const int vr = row >> 1;
  const int ch = (((row & 1) << 2) | chunk) ^ (vr & 7);
  return *(const bf16x8*)(R + vr * 64 + ch * 8);
}

// ---------------------------------------------------------------------------
// e3p: 128x128 tile, BK=32, 256 thr (4 waves 2x2, wave 64x64), 3x16KB LDS
// (3 blocks/CU), stage issued 2 iters ahead, counted vmcnt(4). (r10: 741 TF,
// MfmaUtil 31%, 0 bank conflicts.)
// EPI: 0=QK split (C0=Qcat scaled 1/32 + b0, C1=Kcat + b1)
//      1=theta->cat half (ps=z?1:preScale, mul=z?1:es)
//      2=bf16 plain  3=f32+colbias  4=f32 plain
// ---------------------------------------------------------------------------
template <int EPI>
__global__ __launch_bounds__(256, 3) void e3p(
    const u16* __restrict__ A, long long lda, long long sAz,
    const u16* __restrict__ B, long long ldb, long long sBz,
    void* __restrict__ C0, void* __restrict__ C1,
    long long ldc, long long sCz, int K,
    const float* __restrict__ b0, const float* __restrict__ b1,
    float preScale, const float* __restrict__ esp) {
  constexpr int HALF = 4096;
  constexpr int BUFU = 2 * HALF;
  __shared__ __align__(16) u16 lds[3 * BUFU];

  const int gx = gridDim.x, S = gx * gridDim.y;
  const int hw = blockIdx.y * gx + blockIdx.x;
  const int l = (hw & 7) * (S >> 3) + (hw >> 3);
  const int bx = l % gx, by = l / gx;
  const int z = blockIdx.z;
  const long long tM = (long long)by * 128;
  const long long tN = (long long)bx * 128;
  const u16* GA = A + z * sAz + tM * lda;
  const u16* GB = B + z * sBz + tN * ldb;
  const int tid = threadIdx.x;
  const int NT = K >> 5;

  stage128(GA, lda, 0, lds, tid);
  stage128(GB, ldb, 0, lds + HALF, tid);
  stage128(GA, lda, 32, lds + BUFU, tid);
  stage128(GB, ldb, 32, lds + BUFU + HALF, tid);

  const int wid = tid >> 6, lane = tid & 63;
  const int wr = (wid >> 1) * 64, wc = (wid & 1) * 64;
  const int lr = lane & 15, cA = lane >> 4;
  f32x4 acc[4][4] = {};

  for (int t = 0; t < NT; ++t) {
    if (t < NT - 1) vmwait<4>(); else vmwait<0>();
    __builtin_amdgcn_s_barrier();
    if (t + 2 < NT) {
      u16* nxt = lds + ((t + 2) % 3) * BUFU;
      stage128(GA, lda, (t + 2) * 32, nxt, tid);
      stage128(GB, ldb, (t + 2) * 32, nxt + HALF, tid);
    }
    const u16* cur = lds + (t % 3) * BUFU;
    bf16x8 a[4], b[4];
#pragma unroll
    for (int m = 0; m < 4; ++m) a[m] = fr4(cur, wr + m * 16 + lr, cA);
#pragma unroll
    for (int n = 0; n < 4; ++n) b[n] = fr4(cur + HALF, wc + n * 16 + lr, cA);
#pragma unroll
    for (int m = 0; m < 4; ++m)
#pragma unroll
      for (int n = 0; n < 4; ++n)
        acc[m][n] = __builtin_amdgcn_mfma_f32_16x16x32_bf16(a[m], b[n],
                                                            acc[m][n], 0, 0, 0);
  }

  // epilogue: C/D map col=lane&15, row=(lane>>4)*4+reg
  const int rr = (lane >> 4) << 2;
  float ps = preScale, mul = 1.0f;
  if constexpr (EPI == 1) {
    ps = (z == 0) ? preScale : 1.0f;
    mul = (z == 0) ? esp[0] : 1.0f;
  }
#pragma unroll
  for (int m = 0; m < 4; ++m) {
#pragma unroll
    for (int n = 0; n < 4; ++n) {
      const int col = (int)tN + wc + n * 16 + lr;
#pragma unroll
      for (int r = 0; r < 4; ++r) {
        const long long row = tM + wr + m * 16 + rr + r;
        const float v = acc[m][n][r];
        if constexpr (EPI == 0) {
          const int g = col >> 10, cc = col & 1023;
          if (g == 0) ((u16*)C0)[row * 2048 + cc] = f2b((v + b0[cc]) * 0.03125f);
          else        ((u16*)C1)[row * 2048 + cc] = f2b(v + b1[cc]);
        } else if constexpr (EPI == 1) {
          const float tt = v * ps + b0[col];
          const float sg = 1.f / (1.f + __expf(-tt));
          ((u16*)C0)[z * sCz + row * ldc + col] = f2b(mul * cospif(sg));
        } else if constexpr (EPI == 2) {
          ((u16*)C0)[z * sCz + row * ldc + col] = f2b(v);
        } else if constexpr (EPI == 3) {
          ((float*)C0)[z * sCz + row * ldc + col] = v + b0[col];
        } else {
          ((float*)C0)[z * sCz + row * ldc + col] = v;
        }
      }
    }
  }
}

// bfin[i] = sum_k bv[k]*Wo[k][i] + bo[i]; one output per block (1024 blocks)
__global__ __launch_bounds__(256) void bias_fold(
    const float* __restrict__ bv, const float* __restrict__ Wo,
    const float* __restrict__ bo, float* __restrict__ out) {
  const int i = blockIdx.x;
  float acc = 0.f;
  for (int k = threadIdx.x; k < 1024; k += 256)
    acc += bv[k] * Wo[(long long)k * 1024 + i];
  __shared__ float red[256];
  red[threadIdx.x] = acc;
  __syncthreads();
  for (int s = 128; s > 0; s >>= 1) {
    if (threadIdx.x < s) red[threadIdx.x] += red[threadIdx.x + s];
    __syncthreads();
  }
  if (threadIdx.x == 0) out[i] = red[0] + bo[i];
}

// row softmax over [8192][2048]: fp32 in-place + bf16 copy
__global__ __launch_bounds__(256) void softmax_rows(float* __restrict__ L,
                                                    u16* __restrict__ AB) {
  const long long row = blockIdx.x;
  float4* p4 = (float4*)(L + row * 2048);
  const int tid = threadIdx.x;
  float4 a = p4[tid], b = p4[tid + 256];
  float m = fmaxf(fmaxf(fmaxf(a.x, a.y), fmaxf(a.z, a.w)),
                  fmaxf(fmaxf(b.x, b.y), fmaxf(b.z, b.w)));
#pragma unroll
  for (int o = 32; o > 0; o >>= 1) m = fmaxf(m, __shfl_xor(m, o));
  __shared__ float rmax[4], rsum[4];
  const int wid = tid >> 6, lane = tid & 63;
  if (lane == 0) rmax[wid] = m;
  __syncthreads();
  m = fmaxf(fmaxf(rmax[0], rmax[1]), fmaxf(rmax[2], rmax[3]));
  a.x = __expf(a.x - m); a.y = __expf(a.y - m);
  a.z = __expf(a.z - m); a.w = __expf(a.w - m);
  b.x = __expf(b.x - m); b.y = __expf(b.y - m);
  b.z = __expf(b.z - m); b.w = __expf(b.w - m);
  float s = a.x + a.y + a.z + a.w + b.x + b.y + b.z + b.w;
#pragma unroll
  for (int o = 32; o > 0; o >>= 1) s += __shfl_xor(s, o);
  if (lane == 0) rsum[wid] = s;
  __syncthreads();
  s = rsum[0] + rsum[1] + rsum[2] + rsum[3];
  const float inv = 1.0f / s;
  a.x *= inv; a.y *= inv; a.z *= inv; a.w *= inv;
  b.x *= inv; b.y *= inv; b.z *= inv; b.w *= inv;
  p4[tid] = a;
  p4[tid + 256] = b;
  ushort4* o4 = (ushort4*)(AB + row * 2048);
  o4[tid]       = make_ushort4(f2b(a.x), f2b(a.y), f2b(a.z), f2b(a.w));
  o4[tid + 256] = make_ushort4(f2b(b.x), f2b(b.y), f2b(b.z), f2b(b.w));
}

__global__ __launch_bounds__(256) void cvt_x(const float* __restrict__ X,
                                             u16* __restrict__ XB) {
  const int i = blockIdx.x * 256 + threadIdx.x;
  float4 v = ((const float4*)X)[i];
  ((ushort4*)XB)[i] = make_ushort4(f2b(v.x), f2b(v.y), f2b(v.z), f2b(v.w));
}

// z0..3: transpose {Wq,Wk,Wt,Wo} -> slots {0,1,2,3}; z4: plain Wv -> slot 4
__global__ void cvt_w(const float* __restrict__ Wq, const float* __restrict__ Wk,
                      const float* __restrict__ Wt, const float* __restrict__ Wo,
                      const float* __restrict__ Wv, u16* __restrict__ WT) {
  __shared__ float t[32][33];
  const int z = blockIdx.z;
  const float* W = (z == 0) ? Wq : (z == 1) ? Wk : (z == 2) ? Wt
                 : (z == 3) ? Wo : Wv;
  u16* D = WT + ((long long)z << 20);
  const int c0 = blockIdx.x * 32, r0 = blockIdx.y * 32;
  const int tx = threadIdx.x, ty = threadIdx.y;
  if (z == 4) {
#pragma unroll
    for (int i = 0; i < 4; ++i) {
      const long long idx = (long long)(r0 + ty + i * 8) * 1024 + c0 + tx;
      D[idx] = f2b(W[idx]);
    }
    return;
  }
#pragma unroll
  for (int i = 0; i < 4; ++i)
    t[ty + i * 8][tx] = W[(long long)(r0 + ty + i * 8) * 1024 + c0 + tx];
  __syncthreads();
#pragma unroll
  for (int i = 0; i < 4; ++i)
    D[(long long)(c0 + ty + i * 8) * 1024 + r0 + tx] = f2b(t[tx][ty + i * 8]);
}

extern "C" void kernel_launch(void* const* d_in, const int* in_sizes, int n_in,
                              void* d_out, int out_size, void* d_ws,
                              size_t ws_size, hipStream_t stream) {
  const float* x  = (const float*)d_in[0];
  const float* Wq = (const float*)d_in[1];
  const float* bq = (const float*)d_in[2];
  const float* Wk = (const float*)d_in[3];
  const float* bk = (const float*)d_in[4];
  const float* Wv = (const float*)d_in[5];
  const float* bv = (const float*)d_in[6];
  const float* Wt = (const float*)d_in[7];
  const float* bt = (const float*)d_in[8];
  const float* Wo = (const float*)d_in[9];
  const float* bo = (const float*)d_in[10];
  const float* es = (const float*)d_in[11];

  char* ws = (char*)d_ws;
  // WT slots (1 MiB-u16 = 2 MB each): 0=WqT 1=WkT 2=WtT 3=WoT 4=WvB 5=WvoT
  u16* WT    = (u16*)(ws);                   // 12 MB
  float* BF  = (float*)(ws + 12582912);      // bfin[1024]
  u16* XB    = (u16*)(ws + 12587008);        // [8192,1024] bf16 (16 MB)
  u16* Qcat  = (u16*)(ws + 29364224);        // [8192,2048]: Q/32 | es*r_q
  u16* Kcat  = Qcat + 16777216;              // [8192,2048]: K | r_k
  u16* XVT   = (u16*)(ws + 96473088);        // [4][1024,2048]: (x@Wvo)^T
  u16* ATT   = Qcat;                         // attn bf16 reuse

  float* outO = (float*)d_out;               // [4,2048,1024]
  float* outA = outO + 8388608;              // [4,2048,2048]

  cvt_x<<<8192, 256, 0, stream>>>(x, XB);
  cvt_w<<<dim3(32, 32, 5), dim3(32, 8), 0, stream>>>(Wq, Wk, Wt, Wo, Wv, WT);
  bias_fold<<<1024, 256, 0, stream>>>(bv, Wo, bo, BF);
  // WvoT = WoT @ WvB^T -> slot 5 (grid 64)
  e3p<2><<<dim3(8, 8, 1), 256, 0, stream>>>(
      WT + (3LL << 20), 1024, 0, WT + (4LL << 20), 1024, 0,
      WT + (5LL << 20), nullptr, 1024, 0, 1024, nullptr, nullptr, 1.f, nullptr);
  // QK projection: X @ [WqT|WkT]^T -> Qcat/Kcat halves (grid 1024)
  e3p<0><<<dim3(16, 64, 1), 256, 0, stream>>>(
      XB, 1024, 0, WT, 1024, 0, Qcat, Kcat, 2048, 0, 1024,
      bq, bk, 1.f, nullptr);
  // theta (z0: Qcat/32 -> es*r_q, ps=32; z1: Kcat -> r_k, ps=1), grid 1024
  e3p<1><<<dim3(8, 64, 2), 256, 0, stream>>>(
      Qcat, 2048, 16777216, WT + (2LL << 20), 1024, 0, Qcat + 1024, nullptr,
      2048, 16777216, 1024, bt, nullptr, 32.f, es);
  // XVT = WvoT @ XB^T  (grid 512)
  e3p<2><<<dim3(16, 8, 4), 256, 0, stream>>>(
      WT + (5LL << 20), 1024, 0, XB, 1024, 2097152,
      XVT, nullptr, 2048, 2097152, 1024, nullptr, nullptr, 1.f, nullptr);
  // logits = Qcat @ Kcat^T (K=2048) -> outA (grid 1024)
  e3p<4><<<dim3(16, 16, 4), 256, 0, stream>>>(
      Qcat, 2048, 4194304, Kcat, 2048, 4194304,
      outA, nullptr, 2048, 4194304, 2048, nullptr, nullptr, 1.f, nullptr);
  softmax_rows<<<8192, 256, 0, stream>>>(outA, ATT);
  // out = ATT @ XVT^T + bfin  (grid 512)
  e3p<3><<<dim3(8, 16, 4), 256, 0, stream>>>(
      ATT, 2048, 4194304, XVT, 2048, 2097152,
      outO, nullptr, 1024, 2097152, 2048, BF, nullptr, 1.f, nullptr);
}

// Round 14
// 316.525 us; speedup vs baseline: 1.8366x; 1.0725x over previous
//
#include <hip/hip_runtime.h>
#include <cstdint>

typedef unsigned short u16;
typedef __attribute__((ext_vector_type(8))) short bf16x8;
typedef __attribute__((ext_vector_type(4))) float f32x4;

__device__ __forceinline__ u16 f2b(float x) {
  unsigned u = __float_as_uint(x);
  u += 0x7FFFu + ((u >> 16) & 1u);
  return (u16)(u >> 16);
}

__device__ __forceinline__ void gload16(const void* g, void* l) {
  __builtin_amdgcn_global_load_lds(
      (const __attribute__((address_space(1))) void*)g,
      (__attribute__((address_space(3))) void*)l, 16, 0, 0);
}

template <int N>
__device__ __forceinline__ void vmwait() {
  if constexpr (N == 0) asm volatile("s_waitcnt vmcnt(0)" ::: "memory");
  else if constexpr (N == 4) asm volatile("s_waitcnt vmcnt(4)" ::: "memory");
}

// ---------------------------------------------------------------------------
// 128x32 bf16 slice as 64 virtual rows of 128 B (8 x 16 B chunks), chunk
// XOR (vrow&7): measured ZERO bank conflicts (r10/r13). Both-sides rule
// (m231): LDS dest linear, global source inverse-swizzled, read same
// involution.
// ---------------------------------------------------------------------------
__device__ __forceinline__ void stage128(const u16* __restrict__ G,
                                         long long ld, int kb,
                                         u16* Ldst, int tid) {
#pragma unroll
  for (int j = 0; j < 2; ++j) {
    const int P = j * 256 + tid;
    const int vr = P >> 3;
    const int ch = (P & 7) ^ (vr & 7);
    const int r = vr * 2 + (ch >> 2), c = ch & 3;
    gload16(G + (long long)r * ld + kb + c * 8, Ldst + P * 8);
  }
}

__device__ __forceinline__ bf16x8 fr4(const u16* R, int row, int chunk) {
  const int vr = row >> 1;
  const int ch = (((row & 1) << 2) | chunk) ^ (vr & 7);
  return *(const bf16x8*)(R + vr * 64 + ch * 8);
}

// XCD-aware bijective swizzle within a role's sub-grid (S % 8 == 0)
__device__ __forceinline__ void swz_xcd(int hw, int S, int gx,
                                        int& bx, int& by) {
  const int l = (hw & 7) * (S >> 3) + (hw >> 3);
  bx = l % gx;
  by = l / gx;
}

// ---------------------------------------------------------------------------
// gemm_core: the r10-proven e3p body. 128x128 tile, BK=32, 256 thr (4 waves
// 2x2, wave 64x64), 3x16KB LDS (3 blocks/CU), stage issued 2 iters ahead,
// counted vmcnt(4). (r10/r13: 741 TF, MfmaUtil 31%, 0 bank conflicts.)
// EPI: 0=QK split  1=theta->cat half  2=bf16  3=f32+colbias  4=f32 plain
// ---------------------------------------------------------------------------
template <int EPI>
__device__ __forceinline__ void gemm_core(
    u16* lds, int bx, int by, int z,
    const u16* __restrict__ A, long long lda, long long sAz,
    const u16* __restrict__ B, long long ldb, long long sBz,
    void* __restrict__ C0, void* __restrict__ C1,
    long long ldc, long long sCz, int K,
    const float* __restrict__ b0, const float* __restrict__ b1,
    float preScale, const float* __restrict__ esp) {
  constexpr int HALF = 4096;
  constexpr int BUFU = 2 * HALF;
  const long long tM = (long long)by * 128;
  const long long tN = (long long)bx * 128;
  const u16* GA = A + z * sAz + tM * lda;
  const u16* GB = B + z * sBz + tN * ldb;
  const int tid = threadIdx.x;
  const int NT = K >> 5;

  stage128(GA, lda, 0, lds, tid);
  stage128(GB, ldb, 0, lds + HALF, tid);
  stage128(GA, lda, 32, lds + BUFU, tid);
  stage128(GB, ldb, 32, lds + BUFU + HALF, tid);

  const int wid = tid >> 6, lane = tid & 63;
  const int wr = (wid >> 1) * 64, wc = (wid & 1) * 64;
  const int lr = lane & 15, cA = lane >> 4;
  f32x4 acc[4][4] = {};

  for (int t = 0; t < NT; ++t) {
    if (t < NT - 1) vmwait<4>(); else vmwait<0>();
    __builtin_amdgcn_s_barrier();
    if (t + 2 < NT) {
      u16* nxt = lds + ((t + 2) % 3) * BUFU;
      stage128(GA, lda, (t + 2) * 32, nxt, tid);
      stage128(GB, ldb, (t + 2) * 32, nxt + HALF, tid);
    }
    const u16* cur = lds + (t % 3) * BUFU;
    bf16x8 a[4], b[4];
#pragma unroll
    for (int m = 0; m < 4; ++m) a[m] = fr4(cur, wr + m * 16 + lr, cA);
#pragma unroll
    for (int n = 0; n < 4; ++n) b[n] = fr4(cur + HALF, wc + n * 16 + lr, cA);
#pragma unroll
    for (int m = 0; m < 4; ++m)
#pragma unroll
      for (int n = 0; n < 4; ++n)
        acc[m][n] = __builtin_amdgcn_mfma_f32_16x16x32_bf16(a[m], b[n],
                                                            acc[m][n], 0, 0, 0);
  }

  // epilogue: C/D map col=lane&15, row=(lane>>4)*4+reg
  const int rr = (lane >> 4) << 2;
  float ps = preScale, mul = 1.0f;
  if constexpr (EPI == 1) {
    ps = (z == 0) ? preScale : 1.0f;
    mul = (z == 0) ? esp[0] : 1.0f;
  }
#pragma unroll
  for (int m = 0; m < 4; ++m) {
#pragma unroll
    for (int n = 0; n < 4; ++n) {
      const int col = (int)tN + wc + n * 16 + lr;
#pragma unroll
      for (int r = 0; r < 4; ++r) {
        const long long row = tM + wr + m * 16 + rr + r;
        const float v = acc[m][n][r];
        if constexpr (EPI == 0) {
          const int g = col >> 10, cc = col & 1023;
          if (g == 0) ((u16*)C0)[row * 2048 + cc] = f2b((v + b0[cc]) * 0.03125f);
          else        ((u16*)C1)[row * 2048 + cc] = f2b(v + b1[cc]);
        } else if constexpr (EPI == 1) {
          const float tt = v * ps + b0[col];
          const float sg = 1.f / (1.f + __expf(-tt));
          ((u16*)C0)[z * sCz + row * ldc + col] = f2b(mul * cospif(sg));
        } else if constexpr (EPI == 2) {
          ((u16*)C0)[z * sCz + row * ldc + col] = f2b(v);
        } else if constexpr (EPI == 3) {
          ((float*)C0)[z * sCz + row * ldc + col] = v + b0[col];
        } else {
          ((float*)C0)[z * sCz + row * ldc + col] = v;
        }
      }
    }
  }
}

// standalone e3p wrapper (scores, final)
template <int EPI>
__global__ __launch_bounds__(256, 3) void e3p(
    const u16* __restrict__ A, long long lda, long long sAz,
    const u16* __restrict__ B, long long ldb, long long sBz,
    void* __restrict__ C0, long long ldc, long long sCz, int K,
    const float* __restrict__ b0) {
  __shared__ __align__(16) u16 lds[3 * 8192];
  int bx, by;
  swz_xcd(blockIdx.y * gridDim.x + blockIdx.x, gridDim.x * gridDim.y,
          gridDim.x, bx, by);
  gemm_core<EPI>(lds, bx, by, blockIdx.z, A, lda, sAz, B, ldb, sBz,
                 C0, nullptr, ldc, sCz, K, b0, nullptr, 1.f, nullptr);
}

// merged: QK projection (blocks 0..1023) + WvoT prep (1024..1087)
__global__ __launch_bounds__(256, 3) void qk_wvo(
    const u16* __restrict__ XB, u16* __restrict__ WT,
    u16* __restrict__ Qc, u16* __restrict__ Kc,
    const float* __restrict__ bq, const float* __restrict__ bk) {
  __shared__ __align__(16) u16 lds[3 * 8192];
  const int id = blockIdx.x;
  if (id < 1024) {
    int bx, by;
    swz_xcd(id, 1024, 16, bx, by);
    gemm_core<0>(lds, bx, by, 0, XB, 1024, 0, WT, 1024, 0,
                 Qc, Kc, 2048, 0, 1024, bq, bk, 1.f, nullptr);
  } else {
    int bx, by;
    swz_xcd(id - 1024, 64, 8, bx, by);
    gemm_core<2>(lds, bx, by, 0, WT + (3LL << 20), 1024, 0,
                 WT + (4LL << 20), 1024, 0, WT + (5LL << 20), nullptr,
                 1024, 0, 1024, nullptr, nullptr, 1.f, nullptr);
  }
}

// merged: theta (blocks 0..1023) + XVT (1024..1535); 1536 = 2x768 rounds
__global__ __launch_bounds__(256, 3) void theta_xvt(
    u16* __restrict__ Qcat, const u16* __restrict__ WT,
    const u16* __restrict__ XB, u16* __restrict__ XVT_,
    const float* __restrict__ bt, const float* __restrict__ esp) {
  __shared__ __align__(16) u16 lds[3 * 8192];
  const int id = blockIdx.x;
  if (id < 1024) {
    const int z = id >> 9;
    int bx, by;
    swz_xcd(id & 511, 512, 8, bx, by);
    gemm_core<1>(lds, bx, by, z, Qcat, 2048, 16777216LL,
                 WT + (2LL << 20), 1024, 0, Qcat + 1024, nullptr,
                 2048, 16777216LL, 1024, bt, nullptr, 32.f, esp);
  } else {
    const int e = id - 1024, z = e >> 7;
    int bx, by;
    swz_xcd(e & 127, 128, 16, bx, by);
    gemm_core<2>(lds, bx, by, z, WT + (5LL << 20), 1024, 0,
                 XB, 1024, 2097152LL, XVT_, nullptr,
                 2048, 2097152LL, 1024, nullptr, nullptr, 1.f, nullptr);
  }
}

// merged prep: cvt_x (0..8191) + cvt_w (8192..13311) + bias_fold (13312..14335)
__global__ __launch_bounds__(256) void prep_all(
    const float* __restrict__ x,
    const float* __restrict__ Wq, const float* __restrict__ Wk,
    const float* __restrict__ Wt, const float* __restrict__ Wo,
    const float* __restrict__ Wv, const float* __restrict__ bv,
    const float* __restrict__ bo,
    u16* __restrict__ XB, u16* __restrict__ WT, float* __restrict__ BF) {
  __shared__ float sh[32][33];
  const int id = blockIdx.x;
  const int thr = threadIdx.x;
  if (id < 8192) {
    // cvt_x: fp32 -> bf16, 4 elems/thread
    const int i = id * 256 + thr;
    float4 v = ((const float4*)x)[i];
    ((ushort4*)XB)[i] = make_ushort4(f2b(v.x), f2b(v.y), f2b(v.z), f2b(v.w));
  } else if (id < 13312) {
    // cvt_w: z0..3 transpose {Wq,Wk,Wt,Wo} -> slots 0..3; z4 plain Wv -> 4
    const int w = id - 8192;
    const int z = w >> 10, rem = w & 1023;
    const int cx = rem & 31, cy = rem >> 5;
    const float* W = (z == 0) ? Wq : (z == 1) ? Wk : (z == 2) ? Wt
                   : (z == 3) ? Wo : Wv;
    u16* D = WT + ((long long)z << 20);
    const int c0 = cx * 32, r0 = cy * 32;
    const int tx = thr & 31, ty = thr >> 5;
    if (z == 4) {
#pragma unroll
      for (int i = 0; i < 4; ++i) {
        const long long idx = (long long)(r0 + ty + i * 8) * 1024 + c0 + tx;
        D[idx] = f2b(W[idx]);
      }
      return;
    }
#pragma unroll
    for (int i = 0; i < 4; ++i)
      sh[ty + i * 8][tx] = W[(long long)(r0 + ty + i * 8) * 1024 + c0 + tx];
    __syncthreads();
#pragma unroll
    for (int i = 0; i < 4; ++i)
      D[(long long)(c0 + ty + i * 8) * 1024 + r0 + tx] = f2b(sh[tx][ty + i * 8]);
  } else {
    // bias_fold: bfin[i] = sum_k bv[k]*Wo[k][i] + bo[i]
    const int i = id - 13312;
    float acc = 0.f;
    for (int k = thr; k < 1024; k += 256)
      acc += bv[k] * Wo[(long long)k * 1024 + i];
    float* red = &sh[0][0];
    red[thr] = acc;
    __syncthreads();
    for (int s = 128; s > 0; s >>= 1) {
      if (thr < s) red[thr] += red[thr + s];
      __syncthreads();
    }
    if (thr == 0) BF[i] = red[0] + bo[i];
  }
}

// row softmax over [8192][2048]: fp32 in-place + bf16 copy
__global__ __launch_bounds__(256) void softmax_rows(float* __restrict__ L,
                                                    u16* __restrict__ AB) {
  const long long row = blockIdx.x;
  float4* p4 = (float4*)(L + row * 2048);
  const int tid = threadIdx.x;
  float4 a = p4[tid], b = p4[tid + 256];
  float m = fmaxf(fmaxf(fmaxf(a.x, a.y), fmaxf(a.z, a.w)),
                  fmaxf(fmaxf(b.x, b.y), fmaxf(b.z, b.w)));
#pragma unroll
  for (int o = 32; o > 0; o >>= 1) m = fmaxf(m, __shfl_xor(m, o));
  __shared__ float rmax[4], rsum[4];
  const int wid = tid >> 6, lane = tid & 63;
  if (lane == 0) rmax[wid] = m;
  __syncthreads();
  m = fmaxf(fmaxf(rmax[0], rmax[1]), fmaxf(rmax[2], rmax[3]));
  a.x = __expf(a.x - m); a.y = __expf(a.y - m);
  a.z = __expf(a.z - m); a.w = __expf(a.w - m);
  b.x = __expf(b.x - m); b.y = __expf(b.y - m);
  b.z = __expf(b.z - m); b.w = __expf(b.w - m);
  float s = a.x + a.y + a.z + a.w + b.x + b.y + b.z + b.w;
#pragma unroll
  for (int o = 32; o > 0; o >>= 1) s += __shfl_xor(s, o);
  if (lane == 0) rsum[wid] = s;
  __syncthreads();
  s = rsum[0] + rsum[1] + rsum[2] + rsum[3];
  const float inv = 1.0f / s;
  a.x *= inv; a.y *= inv; a.z *= inv; a.w *= inv;
  b.x *= inv; b.y *= inv; b.z *= inv; b.w *= inv;
  p4[tid] = a;
  p4[tid + 256] = b;
  ushort4* o4 = (ushort4*)(AB + row * 2048);
  o4[tid]       = make_ushort4(f2b(a.x), f2b(a.y), f2b(a.z), f2b(a.w));
  o4[tid + 256] = make_ushort4(f2b(b.x), f2b(b.y), f2b(b.z), f2b(b.w));
}

extern "C" void kernel_launch(void* const* d_in, const int* in_sizes, int n_in,
                              void* d_out, int out_size, void* d_ws,
                              size_t ws_size, hipStream_t stream) {
  const float* x  = (const float*)d_in[0];
  const float* Wq = (const float*)d_in[1];
  const float* bq = (const float*)d_in[2];
  const float* Wk = (const float*)d_in[3];
  const float* bk = (const float*)d_in[4];
  const float* Wv = (const float*)d_in[5];
  const float* bv = (const float*)d_in[6];
  const float* Wt = (const float*)d_in[7];
  const float* bt = (const float*)d_in[8];
  const float* Wo = (const float*)d_in[9];
  const float* bo = (const float*)d_in[10];
  const float* es = (const float*)d_in[11];

  char* ws = (char*)d_ws;
  // WT slots (1 MiB-u16 = 2 MB each): 0=WqT 1=WkT 2=WtT 3=WoT 4=WvB 5=WvoT
  u16* WT    = (u16*)(ws);                   // 12 MB
  float* BF  = (float*)(ws + 12582912);      // bfin[1024]
  u16* XB    = (u16*)(ws + 12587008);        // [8192,1024] bf16
  u16* Qcat  = (u16*)(ws + 29364224);        // [8192,2048]: Q/32 | es*r_q
  u16* Kcat  = Qcat + 16777216;              // [8192,2048]: K | r_k
  u16* XVT   = (u16*)(ws + 96473088);        // [4][1024,2048]: (x@Wvo)^T
  u16* ATT   = Qcat;                         // attn bf16 reuse

  float* outO = (float*)d_out;               // [4,2048,1024]
  float* outA = outO + 8388608;              // [4,2048,2048]

  // 1. all preps (cvt_x + cvt_w + bias_fold)
  prep_all<<<14336, 256, 0, stream>>>(x, Wq, Wk, Wt, Wo, Wv, bv, bo,
                                      XB, WT, BF);
  // 2. QK projection + WvoT prep
  qk_wvo<<<1088, 256, 0, stream>>>(XB, WT, Qcat, Kcat, bq, bk);
  // 3. theta (both halves) + XVT
  theta_xvt<<<1536, 256, 0, stream>>>(Qcat, WT, XB, XVT, bt, es);
  // 4. logits = Qcat @ Kcat^T (K=2048) -> outA
  e3p<4><<<dim3(16, 16, 4), 256, 0, stream>>>(
      Qcat, 2048, 4194304, Kcat, 2048, 4194304,
      outA, 2048, 4194304, 2048, nullptr);
  // 5. softmax in-place + bf16 copy
  softmax_rows<<<8192, 256, 0, stream>>>(outA, ATT);
  // 6. out = ATT @ XVT^T + bfin
  e3p<3><<<dim3(8, 16, 4), 256, 0, stream>>>(
      ATT, 2048, 4194304, XVT, 2048, 2097152,
      outO, 1024, 2097152, 2048, BF);
}

// Round 15
// 306.608 us; speedup vs baseline: 1.8960x; 1.0323x over previous
//
#include <hip/hip_runtime.h>
#include <cstdint>

typedef unsigned short u16;
typedef __attribute__((ext_vector_type(8))) short bf16x8;
typedef __attribute__((ext_vector_type(4))) float f32x4;

__device__ __forceinline__ u16 f2b(float x) {
  unsigned u = __float_as_uint(x);
  u += 0x7FFFu + ((u >> 16) & 1u);
  return (u16)(u >> 16);
}

__device__ __forceinline__ void gload16(const void* g, void* l) {
  __builtin_amdgcn_global_load_lds(
      (const __attribute__((address_space(1))) void*)g,
      (__attribute__((address_space(3))) void*)l, 16, 0, 0);
}

template <int N>
__device__ __forceinline__ void vmwait() {
  if constexpr (N == 0) asm volatile("s_waitcnt vmcnt(0)" ::: "memory");
  else if constexpr (N == 4) asm volatile("s_waitcnt vmcnt(4)" ::: "memory");
  else if constexpr (N == 6) asm volatile("s_waitcnt vmcnt(6)" ::: "memory");
}

// ---------------------------------------------------------------------------
// 128x32 bf16 slice as 64 virtual rows of 128 B (8 x 16 B chunks), chunk
// XOR (vrow&7): measured ZERO bank conflicts (r10/r13/r14). Both-sides rule
// (m231): LDS dest linear, global source inverse-swizzled, read same
// involution.
// ---------------------------------------------------------------------------
__device__ __forceinline__ void stage128(const u16* __restrict__ G,
                                         long long ld, int kb,
                                         u16* Ldst, int tid) {
#pragma unroll
  for (int j = 0; j < 2; ++j) {
    const int P = j * 256 + tid;
    const int vr = P >> 3;
    const int ch = (P & 7) ^ (vr & 7);
    const int r = vr * 2 + (ch >> 2), c = ch & 3;
    gload16(G + (long long)r * ld + kb + c * 8, Ldst + P * 8);
  }
}

__device__ __forceinline__ bf16x8 fr4(const u16* R, int row, int chunk) {
  const int vr = row >> 1;
  const int ch = (((row & 1) << 2) | chunk) ^ (vr & 7);
  return *(const bf16x8*)(R + vr * 64 + ch * 8);
}

// XCD-aware bijective swizzle within a role's sub-grid (S % 8 == 0)
__device__ __forceinline__ void swz_xcd(int hw, int S, int gx,
                                        int& bx, int& by) {
  const int l = (hw & 7) * (S >> 3) + (hw >> 3);
  bx = l % gx;
  by = l / gx;
}

// ---------------------------------------------------------------------------
// gemm_core: 128x128 tile, BK=32, 256 thr (4 waves 2x2, wave 64x64), 3x16KB
// LDS (3 blocks/CU), stage 2 iters ahead, counted vmcnt(4). (741 TF class.)
// EPI: 0=QK split  1=theta->cat half  2=bf16  3=f32+colbias  4=f32 plain
// ---------------------------------------------------------------------------
template <int EPI>
__device__ __forceinline__ void gemm_core(
    u16* lds, int bx, int by, int z,
    const u16* __restrict__ A, long long lda, long long sAz,
    const u16* __restrict__ B, long long ldb, long long sBz,
    void* __restrict__ C0, void* __restrict__ C1,
    long long ldc, long long sCz, int K,
    const float* __restrict__ b0, const float* __restrict__ b1,
    float preScale, const float* __restrict__ esp) {
  constexpr int HALF = 4096;
  constexpr int BUFU = 2 * HALF;
  const long long tM = (long long)by * 128;
  const long long tN = (long long)bx * 128;
  const u16* GA = A + z * sAz + tM * lda;
  const u16* GB = B + z * sBz + tN * ldb;
  const int tid = threadIdx.x;
  const int NT = K >> 5;

  stage128(GA, lda, 0, lds, tid);
  stage128(GB, ldb, 0, lds + HALF, tid);
  stage128(GA, lda, 32, lds + BUFU, tid);
  stage128(GB, ldb, 32, lds + BUFU + HALF, tid);

  const int wid = tid >> 6, lane = tid & 63;
  const int wr = (wid >> 1) * 64, wc = (wid & 1) * 64;
  const int lr = lane & 15, cA = lane >> 4;
  f32x4 acc[4][4] = {};

  for (int t = 0; t < NT; ++t) {
    if (t < NT - 1) vmwait<4>(); else vmwait<0>();
    __builtin_amdgcn_s_barrier();
    if (t + 2 < NT) {
      u16* nxt = lds + ((t + 2) % 3) * BUFU;
      stage128(GA, lda, (t + 2) * 32, nxt, tid);
      stage128(GB, ldb, (t + 2) * 32, nxt + HALF, tid);
    }
    const u16* cur = lds + (t % 3) * BUFU;
    bf16x8 a[4], b[4];
#pragma unroll
    for (int m = 0; m < 4; ++m) a[m] = fr4(cur, wr + m * 16 + lr, cA);
#pragma unroll
    for (int n = 0; n < 4; ++n) b[n] = fr4(cur + HALF, wc + n * 16 + lr, cA);
#pragma unroll
    for (int m = 0; m < 4; ++m)
#pragma unroll
      for (int n = 0; n < 4; ++n)
        acc[m][n] = __builtin_amdgcn_mfma_f32_16x16x32_bf16(a[m], b[n],
                                                            acc[m][n], 0, 0, 0);
  }

  // epilogue: C/D map col=lane&15, row=(lane>>4)*4+reg
  const int rr = (lane >> 4) << 2;
  float ps = preScale, mul = 1.0f;
  if constexpr (EPI == 1) {
    ps = (z == 0) ? preScale : 1.0f;
    mul = (z == 0) ? esp[0] : 1.0f;
  }
#pragma unroll
  for (int m = 0; m < 4; ++m) {
#pragma unroll
    for (int n = 0; n < 4; ++n) {
      const int col = (int)tN + wc + n * 16 + lr;
#pragma unroll
      for (int r = 0; r < 4; ++r) {
        const long long row = tM + wr + m * 16 + rr + r;
        const float v = acc[m][n][r];
        if constexpr (EPI == 0) {
          const int g = col >> 10, cc = col & 1023;
          if (g == 0) ((u16*)C0)[row * 2048 + cc] = f2b((v + b0[cc]) * 0.03125f);
          else        ((u16*)C1)[row * 2048 + cc] = f2b(v + b1[cc]);
        } else if constexpr (EPI == 1) {
          const float tt = v * ps + b0[col];
          const float sg = 1.f / (1.f + __expf(-tt));
          ((u16*)C0)[z * sCz + row * ldc + col] = f2b(mul * cospif(sg));
        } else if constexpr (EPI == 2) {
          ((u16*)C0)[z * sCz + row * ldc + col] = f2b(v);
        } else if constexpr (EPI == 3) {
          ((float*)C0)[z * sCz + row * ldc + col] = v + b0[col];
        } else {
          ((float*)C0)[z * sCz + row * ldc + col] = v;
        }
      }
    }
  }
}

// standalone e3p wrapper (final)
template <int EPI>
__global__ __launch_bounds__(256, 3) void e3p(
    const u16* __restrict__ A, long long lda, long long sAz,
    const u16* __restrict__ B, long long ldb, long long sBz,
    void* __restrict__ C0, long long ldc, long long sCz, int K,
    const float* __restrict__ b0) {
  __shared__ __align__(16) u16 lds[3 * 8192];
  int bx, by;
  swz_xcd(blockIdx.y * gridDim.x + blockIdx.x, gridDim.x * gridDim.y,
          gridDim.x, bx, by);
  gemm_core<EPI>(lds, bx, by, blockIdx.z, A, lda, sAz, B, ldb, sBz,
                 C0, nullptr, ldc, sCz, K, b0, nullptr, 1.f, nullptr);
}

// ---------------------------------------------------------------------------
// e3s: A-frag-reuse wide-wave GEMM (scores). Block 128x256, BK=32, 256 thr
// (4 waves 2Mx2N), wave 64x128: per iter a[4]+b[8] = 12 ds_read_b128 for
// 32 MFMA (0.375 reads/MFMA vs e3p 0.5). 3x24KB LDS (2 blocks/CU), depth-2
// counted vmcnt(6). f32 plain output.
// ---------------------------------------------------------------------------
__global__ __launch_bounds__(256, 2) void e3s(
    const u16* __restrict__ A, long long lda, long long sAz,
    const u16* __restrict__ B, long long ldb, long long sBz,
    float* __restrict__ C, long long ldc, long long sCz, int K) {
  constexpr int AS = 4096;            // u16: A slice 128x32
  constexpr int BS = 8192;            // u16: B slice 256x32
  constexpr int BUFU = AS + BS;       // 24 KB
  __shared__ __align__(16) u16 lds[3 * BUFU];

  int bx, by;
  swz_xcd(blockIdx.y * gridDim.x + blockIdx.x, gridDim.x * gridDim.y,
          gridDim.x, bx, by);
  const int z = blockIdx.z;
  const long long tM = (long long)by * 128;
  const long long tN = (long long)bx * 256;
  const u16* GA = A + z * sAz + tM * lda;
  const u16* GB = B + z * sBz + tN * ldb;
  const int tid = threadIdx.x;
  const int NT = K >> 5;

  // stage one K-tile: A (2 loads/thr) + B lo/hi (2+2 loads/thr) = 6
#define STAGE_S(kb, buf)                                   \
  do {                                                     \
    stage128(GA, lda, (kb), (buf), tid);                   \
    stage128(GB, ldb, (kb), (buf) + AS, tid);              \
    stage128(GB + 128 * ldb, ldb, (kb), (buf) + AS + 4096, tid); \
  } while (0)

  STAGE_S(0, lds);
  STAGE_S(32, lds + BUFU);

  const int wid = tid >> 6, lane = tid & 63;
  const int wr = (wid >> 1) * 64, wc = (wid & 1) * 128;
  const int lr = lane & 15, cA = lane >> 4;
  f32x4 acc[4][8] = {};

  for (int t = 0; t < NT; ++t) {
    if (t < NT - 1) vmwait<6>(); else vmwait<0>();
    __builtin_amdgcn_s_barrier();
    if (t + 2 < NT) STAGE_S((t + 2) * 32, lds + ((t + 2) % 3) * BUFU);
    const u16* cur = lds + (t % 3) * BUFU;
    const u16* Bs = cur + AS + (wid & 1) * 4096;  // wave's 128-row B sub-slab
    bf16x8 a[4], b[8];
#pragma unroll
    for (int m = 0; m < 4; ++m) a[m] = fr4(cur, wr + m * 16 + lr, cA);
#pragma unroll
    for (int n = 0; n < 8; ++n) b[n] = fr4(Bs, n * 16 + lr, cA);
#pragma unroll
    for (int m = 0; m < 4; ++m)
#pragma unroll
      for (int n = 0; n < 8; ++n)
        acc[m][n] = __builtin_amdgcn_mfma_f32_16x16x32_bf16(a[m], b[n],
                                                            acc[m][n], 0, 0, 0);
  }
#undef STAGE_S

  const int rr = (lane >> 4) << 2;
#pragma unroll
  for (int m = 0; m < 4; ++m) {
#pragma unroll
    for (int n = 0; n < 8; ++n) {
      const int col = (int)tN + wc + n * 16 + lr;
#pragma unroll
      for (int r = 0; r < 4; ++r) {
        const long long row = tM + wr + m * 16 + rr + r;
        C[z * sCz + row * ldc + col] = acc[m][n][r];
      }
    }
  }
}

// merged: QK projection (blocks 0..1023) + WvoT prep (1024..1087)
__global__ __launch_bounds__(256, 3) void qk_wvo(
    const u16* __restrict__ XB, u16* __restrict__ WT,
    u16* __restrict__ Qc, u16* __restrict__ Kc,
    const float* __restrict__ bq, const float* __restrict__ bk) {
  __shared__ __align__(16) u16 lds[3 * 8192];
  const int id = blockIdx.x;
  if (id < 1024) {
    int bx, by;
    swz_xcd(id, 1024, 16, bx, by);
    gemm_core<0>(lds, bx, by, 0, XB, 1024, 0, WT, 1024, 0,
                 Qc, Kc, 2048, 0, 1024, bq, bk, 1.f, nullptr);
  } else {
    int bx, by;
    swz_xcd(id - 1024, 64, 8, bx, by);
    gemm_core<2>(lds, bx, by, 0, WT + (3LL << 20), 1024, 0,
                 WT + (4LL << 20), 1024, 0, WT + (5LL << 20), nullptr,
                 1024, 0, 1024, nullptr, nullptr, 1.f, nullptr);
  }
}

// merged: theta (blocks 0..1023) + XVT (1024..1535); 1536 = 2x768 rounds
__global__ __launch_bounds__(256, 3) void theta_xvt(
    u16* __restrict__ Qcat, const u16* __restrict__ WT,
    const u16* __restrict__ XB, u16* __restrict__ XVT_,
    const float* __restrict__ bt, const float* __restrict__ esp) {
  __shared__ __align__(16) u16 lds[3 * 8192];
  const int id = blockIdx.x;
  if (id < 1024) {
    const int z = id >> 9;
    int bx, by;
    swz_xcd(id & 511, 512, 8, bx, by);
    gemm_core<1>(lds, bx, by, z, Qcat, 2048, 16777216LL,
                 WT + (2LL << 20), 1024, 0, Qcat + 1024, nullptr,
                 2048, 16777216LL, 1024, bt, nullptr, 32.f, esp);
  } else {
    const int e = id - 1024, z = e >> 7;
    int bx, by;
    swz_xcd(e & 127, 128, 16, bx, by);
    gemm_core<2>(lds, bx, by, z, WT + (5LL << 20), 1024, 0,
                 XB, 1024, 2097152LL, XVT_, nullptr,
                 2048, 2097152LL, 1024, nullptr, nullptr, 1.f, nullptr);
  }
}

// merged prep: cvt_x (0..8191) + cvt_w (8192..13311) + bias_fold (13312..14335)
__global__ __launch_bounds__(256) void prep_all(
    const float* __restrict__ x,
    const float* __restrict__ Wq, const float* __restrict__ Wk,
    const float* __restrict__ Wt, const float* __restrict__ Wo,
    const float* __restrict__ Wv, const float* __restrict__ bv,
    const float* __restrict__ bo,
    u16* __restrict__ XB, u16* __restrict__ WT, float* __restrict__ BF) {
  __shared__ float sh[32][33];
  const int id = blockIdx.x;
  const int thr = threadIdx.x;
  if (id < 8192) {
    const int i = id * 256 + thr;
    float4 v = ((const float4*)x)[i];
    ((ushort4*)XB)[i] = make_ushort4(f2b(v.x), f2b(v.y), f2b(v.z), f2b(v.w));
  } else if (id < 13312) {
    const int w = id - 8192;
    const int z = w >> 10, rem = w & 1023;
    const int cx = rem & 31, cy = rem >> 5;
    const float* W = (z == 0) ? Wq : (z == 1) ? Wk : (z == 2) ? Wt
                   : (z == 3) ? Wo : Wv;
    u16* D = WT + ((long long)z << 20);
    const int c0 = cx * 32, r0 = cy * 32;
    const int tx = thr & 31, ty = thr >> 5;
    if (z == 4) {
#pragma unroll
      for (int i = 0; i < 4; ++i) {
        const long long idx = (long long)(r0 + ty + i * 8) * 1024 + c0 + tx;
        D[idx] = f2b(W[idx]);
      }
      return;
    }
#pragma unroll
    for (int i = 0; i < 4; ++i)
      sh[ty + i * 8][tx] = W[(long long)(r0 + ty + i * 8) * 1024 + c0 + tx];
    __syncthreads();
#pragma unroll
    for (int i = 0; i < 4; ++i)
      D[(long long)(c0 + ty + i * 8) * 1024 + r0 + tx] = f2b(sh[tx][ty + i * 8]);
  } else {
    const int i = id - 13312;
    float acc = 0.f;
    for (int k = thr; k < 1024; k += 256)
      acc += bv[k] * Wo[(long long)k * 1024 + i];
    float* red = &sh[0][0];
    red[thr] = acc;
    __syncthreads();
    for (int s = 128; s > 0; s >>= 1) {
      if (thr < s) red[thr] += red[thr + s];
      __syncthreads();
    }
    if (thr == 0) BF[i] = red[0] + bo[i];
  }
}

// row softmax over [8192][2048]: fp32 in-place + bf16 copy
__global__ __launch_bounds__(256) void softmax_rows(float* __restrict__ L,
                                                    u16* __restrict__ AB) {
  const long long row = blockIdx.x;
  float4* p4 = (float4*)(L + row * 2048);
  const int tid = threadIdx.x;
  float4 a = p4[tid], b = p4[tid + 256];
  float m = fmaxf(fmaxf(fmaxf(a.x, a.y), fmaxf(a.z, a.w)),
                  fmaxf(fmaxf(b.x, b.y), fmaxf(b.z, b.w)));
#pragma unroll
  for (int o = 32; o > 0; o >>= 1) m = fmaxf(m, __shfl_xor(m, o));
  __shared__ float rmax[4], rsum[4];
  const int wid = tid >> 6, lane = tid & 63;
  if (lane == 0) rmax[wid] = m;
  __syncthreads();
  m = fmaxf(fmaxf(rmax[0], rmax[1]), fmaxf(rmax[2], rmax[3]));
  a.x = __expf(a.x - m); a.y = __expf(a.y - m);
  a.z = __expf(a.z - m); a.w = __expf(a.w - m);
  b.x = __expf(b.x - m); b.y = __expf(b.y - m);
  b.z = __expf(b.z - m); b.w = __expf(b.w - m);
  float s = a.x + a.y + a.z + a.w + b.x + b.y + b.z + b.w;
#pragma unroll
  for (int o = 32; o > 0; o >>= 1) s += __shfl_xor(s, o);
  if (lane == 0) rsum[wid] = s;
  __syncthreads();
  s = rsum[0] + rsum[1] + rsum[2] + rsum[3];
  const float inv = 1.0f / s;
  a.x *= inv; a.y *= inv; a.z *= inv; a.w *= inv;
  b.x *= inv; b.y *= inv; b.z *= inv; b.w *= inv;
  p4[tid] = a;
  p4[tid + 256] = b;
  ushort4* o4 = (ushort4*)(AB + row * 2048);
  o4[tid]       = make_ushort4(f2b(a.x), f2b(a.y), f2b(a.z), f2b(a.w));
  o4[tid + 256] = make_ushort4(f2b(b.x), f2b(b.y), f2b(b.z), f2b(b.w));
}

extern "C" void kernel_launch(void* const* d_in, const int* in_sizes, int n_in,
                              void* d_out, int out_size, void* d_ws,
                              size_t ws_size, hipStream_t stream) {
  const float* x  = (const float*)d_in[0];
  const float* Wq = (const float*)d_in[1];
  const float* bq = (const float*)d_in[2];
  const float* Wk = (const float*)d_in[3];
  const float* bk = (const float*)d_in[4];
  const float* Wv = (const float*)d_in[5];
  const float* bv = (const float*)d_in[6];
  const float* Wt = (const float*)d_in[7];
  const float* bt = (const float*)d_in[8];
  const float* Wo = (const float*)d_in[9];
  const float* bo = (const float*)d_in[10];
  const float* es = (const float*)d_in[11];

  char* ws = (char*)d_ws;
  // WT slots (1 MiB-u16 = 2 MB each): 0=WqT 1=WkT 2=WtT 3=WoT 4=WvB 5=WvoT
  u16* WT    = (u16*)(ws);                   // 12 MB
  float* BF  = (float*)(ws + 12582912);      // bfin[1024]
  u16* XB    = (u16*)(ws + 12587008);        // [8192,1024] bf16
  u16* Qcat  = (u16*)(ws + 29364224);        // [8192,2048]: Q/32 | es*r_q
  u16* Kcat  = Qcat + 16777216;              // [8192,2048]: K | r_k
  u16* XVT   = (u16*)(ws + 96473088);        // [4][1024,2048]: (x@Wvo)^T
  u16* ATT   = Qcat;                         // attn bf16 reuse

  float* outO = (float*)d_out;               // [4,2048,1024]
  float* outA = outO + 8388608;              // [4,2048,2048]

  // 1. all preps (cvt_x + cvt_w + bias_fold)
  prep_all<<<14336, 256, 0, stream>>>(x, Wq, Wk, Wt, Wo, Wv, bv, bo,
                                      XB, WT, BF);
  // 2. QK projection + WvoT prep
  qk_wvo<<<1088, 256, 0, stream>>>(XB, WT, Qcat, Kcat, bq, bk);
  // 3. theta (both halves) + XVT
  theta_xvt<<<1536, 256, 0, stream>>>(Qcat, WT, XB, XVT, bt, es);
  // 4. logits = Qcat @ Kcat^T (K=2048) -> outA   [A/B: e3s wide-wave]
  e3s<<<dim3(8, 16, 4), 256, 0, stream>>>(
      Qcat, 2048, 4194304, Kcat, 2048, 4194304,
      outA, 2048, 4194304, 2048);
  // 5. softmax in-place + bf16 copy
  softmax_rows<<<8192, 256, 0, stream>>>(outA, ATT);
  // 6. out = ATT @ XVT^T + bfin
  e3p<3><<<dim3(8, 16, 4), 256, 0, stream>>>(
      ATT, 2048, 4194304, XVT, 2048, 2097152,
      outO, 1024, 2097152, 2048, BF);
}